// Round 2
// baseline (856.975 us; speedup 1.0000x reference)
//
#include <hip/hip_runtime.h>

#define LSEQ 9216
#define CDIM 128
#define ED   512
#define DI   256
#define NST  16
#define NCH  128
#define CHL  72
#define LOG2E 1.44269504f

#if defined(__has_builtin)
#  if __has_builtin(__builtin_amdgcn_exp2f)
#    define FEXP2(x) __builtin_amdgcn_exp2f(x)
#  endif
#endif
#ifndef FEXP2
#  define FEXP2(x) exp2f(x)
#endif

__device__ __forceinline__ float fsilu(float x) {
  return x / (1.f + FEXP2(-LOG2E * x));
}
__device__ __forceinline__ float fsoftplus(float x) {
  return (x > 20.f) ? x : log1pf(FEXP2(LOG2E * x));
}
// sequence-position p -> original-l, INPUT gather map.
// slice: xz_s[p] = xz[(p%16)*576 + p/16]
__device__ __forceinline__ int lmap(int p, int mode) {
  if (mode == 0) return p;
  if (mode == 1) return LSEQ - 1 - p;
  return (p & 15) * 576 + (p >> 4);
}
// sequence-position p -> original-l, OUTPUT scatter map (inverse permutation).
// slice gather is NOT an involution; inverse is (p%576)*16 + p/576.
__device__ __forceinline__ int lmap_out(int p, int mode) {
  if (mode == 0) return p;
  if (mode == 1) return LSEQ - 1 - p;
  return (p % 576) * 16 + p / 576;
}

// A2[dir][d][n] = -exp(A_log)*log2(e)
__global__ __launch_bounds__(256) void a2_kernel(
    const float* __restrict__ Af, const float* __restrict__ Ab,
    const float* __restrict__ As, float* __restrict__ A2) {
  int i = blockIdx.x * 256 + threadIdx.x;
  if (i >= 3 * DI * NST) return;
  int dir = i / (DI * NST), j = i % (DI * NST);
  const float* src = (dir == 0) ? Af : ((dir == 1) ? Ab : As);
  A2[i] = -expf(src[j]) * LOG2E;
}

// LayerNorm over C at each (b,l): x (B,C,L) -> xn (B,L,C)
__global__ __launch_bounds__(256) void ln_kernel(
    const float* __restrict__ x, const float* __restrict__ w,
    const float* __restrict__ bb, float* __restrict__ xn) {
  __shared__ float xt[CDIM][65];
  __shared__ float ps[4][64], pq[4][64];
  __shared__ float mu_s[64], rs_s[64];
  const int b = blockIdx.y, l0 = blockIdx.x * 64, tid = threadIdx.x;
  for (int idx = tid; idx < CDIM * 64; idx += 256) {
    int c = idx >> 6, ll = idx & 63;
    xt[c][ll] = x[((size_t)(b * CDIM + c)) * LSEQ + l0 + ll];
  }
  __syncthreads();
  {
    int ll = tid & 63, grp = tid >> 6;
    float s = 0.f, q = 0.f;
    for (int c = grp * 32; c < grp * 32 + 32; ++c) {
      float v = xt[c][ll]; s += v; q += v * v;
    }
    ps[grp][ll] = s; pq[grp][ll] = q;
  }
  __syncthreads();
  if (tid < 64) {
    float S = ps[0][tid] + ps[1][tid] + ps[2][tid] + ps[3][tid];
    float Q = pq[0][tid] + pq[1][tid] + pq[2][tid] + pq[3][tid];
    float mu = S * (1.f / 128.f);
    float var = Q * (1.f / 128.f) - mu * mu;
    mu_s[tid] = mu;
    rs_s[tid] = rsqrtf(var + 1e-5f);
  }
  __syncthreads();
  for (int idx = tid; idx < 64 * CDIM; idx += 256) {
    int c = idx & 127, ll = idx >> 7;
    float v = (xt[c][ll] - mu_s[ll]) * rs_s[ll] * w[c] + bb[c];
    xn[((size_t)(b * LSEQ + l0 + ll)) * CDIM + c] = v;
  }
}

// Out[m,n] = sum_k A[m,k]*W[n,k]; A row-major with lda, Out row-major ldo.
__global__ __launch_bounds__(256) void gemm_kernel(
    const float* __restrict__ A, const float* __restrict__ W,
    float* __restrict__ Out, int N, int K, int lda, int ldo) {
  __shared__ __align__(16) float At[32][68];
  __shared__ __align__(16) float Wt[32][68];
  const int tid = threadIdx.x;
  const int tx = tid & 15, ty = tid >> 4;
  const int m0 = blockIdx.x * 64, n0 = blockIdx.y * 64;
  float acc[4][4] = {};
  for (int k0 = 0; k0 < K; k0 += 32) {
    for (int idx = tid; idx < 64 * 32; idx += 256) {
      int ml = idx >> 5, kl = idx & 31;
      int k = k0 + kl;
      At[kl][ml] = (k < K) ? A[(size_t)(m0 + ml) * lda + k] : 0.f;
    }
    for (int idx = tid; idx < 64 * 32; idx += 256) {
      int nl = idx >> 5, kl = idx & 31;
      int k = k0 + kl, n = n0 + nl;
      Wt[kl][nl] = (k < K && n < N) ? W[(size_t)n * K + k] : 0.f;
    }
    __syncthreads();
#pragma unroll
    for (int k = 0; k < 32; ++k) {
      const float4 av = *(const float4*)&At[k][ty * 4];
      const float4 bv = *(const float4*)&Wt[k][tx * 4];
      const float a[4] = {av.x, av.y, av.z, av.w};
      const float bw[4] = {bv.x, bv.y, bv.z, bv.w};
#pragma unroll
      for (int i = 0; i < 4; ++i)
#pragma unroll
        for (int j = 0; j < 4; ++j) acc[i][j] = fmaf(a[i], bw[j], acc[i][j]);
    }
    __syncthreads();
  }
  for (int i = 0; i < 4; ++i) {
    size_t ro = (size_t)(m0 + ty * 4 + i) * ldo + n0 + tx * 4;
#pragma unroll
    for (int j = 0; j < 4; ++j) {
      int n = n0 + tx * 4 + j;
      if (n < N) Out[ro + j] = acc[i][j];
    }
  }
}

// depthwise causal conv4 + bias + silu, reading xz (B,L,512) x-half via lmap
// gather; writes xc (B,Lp,256) in sequence order.
__global__ __launch_bounds__(256) void conv_kernel(
    const float* __restrict__ xz, const float* __restrict__ cw,
    const float* __restrict__ cb, float* __restrict__ xc, int mode) {
  __shared__ float xs[67][64];
  const int p0 = blockIdx.x * 64, d0 = blockIdx.y * 64, b = blockIdx.z;
  const int tid = threadIdx.x;
  for (int idx = tid; idx < 67 * 64; idx += 256) {
    int pp = idx >> 6, dd = idx & 63;
    int q = p0 + pp - 3;
    float v = 0.f;
    if (q >= 0) {
      int l = lmap(q, mode);
      v = xz[((size_t)b * LSEQ + l) * ED + d0 + dd];
    }
    xs[pp][dd] = v;
  }
  __syncthreads();
  const int dd = tid & 63, pg = tid >> 6;
  const int d = d0 + dd;
  const float w0 = cw[d * 4 + 0], w1 = cw[d * 4 + 1];
  const float w2 = cw[d * 4 + 2], w3 = cw[d * 4 + 3];
  const float bias = cb[d];
  for (int pp = pg * 16; pp < pg * 16 + 16; ++pp) {
    float acc = bias + w0 * xs[pp][dd] + w1 * xs[pp + 1][dd] +
                w2 * xs[pp + 2][dd] + w3 * xs[pp + 3][dd];
    xc[((size_t)b * LSEQ + p0 + pp) * DI + d] = fsilu(acc);
  }
}

// phase 1: per chunk, h_out with h0=0 and sum(dt) (chunk decay = exp2(A2*sumdt))
__global__ __launch_bounds__(256) void scan_p1(
    const float* __restrict__ xc, const float* __restrict__ xdbl,
    const float* __restrict__ A2, const float* __restrict__ dtw,
    const float* __restrict__ dtbias, float* __restrict__ hout,
    float* __restrict__ dts) {
  __shared__ float Xl[CHL][24];
  const int c = blockIdx.x, b = blockIdx.y, d = threadIdx.x;
  const int p0 = c * CHL;
  for (int idx = threadIdx.x; idx < CHL * 24; idx += 256) {
    int pr = idx / 24, r = idx % 24;
    Xl[pr][r] = xdbl[((size_t)b * LSEQ + p0 + pr) * 40 + r];
  }
  float a2[NST], h[NST], dw[8];
#pragma unroll
  for (int n = 0; n < NST; ++n) { a2[n] = A2[d * NST + n]; h[n] = 0.f; }
#pragma unroll
  for (int r = 0; r < 8; ++r) dw[r] = dtw[d * 8 + r];
  const float dbias = dtbias[d];
  float dtsum = 0.f;
  __syncthreads();
  for (int pr = 0; pr < CHL; ++pr) {
    const float u = xc[((size_t)b * LSEQ + p0 + pr) * DI + d];
    float raw = dbias;
#pragma unroll
    for (int r = 0; r < 8; ++r) raw = fmaf(dw[r], Xl[pr][r], raw);
    const float dtv = fsoftplus(raw);
    const float dtu = dtv * u;
    dtsum += dtv;
#pragma unroll
    for (int n = 0; n < NST; ++n) {
      float a = FEXP2(dtv * a2[n]);
      h[n] = fmaf(h[n], a, dtu * Xl[pr][8 + n]);
    }
  }
  size_t hb = (((size_t)c * 4 + b) * DI + d) * NST;
#pragma unroll
  for (int n = 0; n < NST; ++n) hout[hb + n] = h[n];
  dts[((size_t)c * 4 + b) * DI + d] = dtsum;
}

// phase 2: sequential combine across chunks (16384 independent states)
__global__ __launch_bounds__(256) void scan_p2(
    const float* __restrict__ hout, const float* __restrict__ dts,
    const float* __restrict__ A2, float* __restrict__ hinit) {
  const int g = blockIdx.x * 256 + threadIdx.x;
  const int b = g >> 12;
  const int rest = g & 4095;  // d*16+n
  const int d = rest >> 4;
  const float a2 = A2[rest];
  float h = 0.f;
  for (int c = 0; c < NCH; ++c) {
    const size_t i16 = (size_t)(c * 4 + b) * 4096 + rest;
    hinit[i16] = h;
    h = hout[i16] + FEXP2(dts[(size_t)(c * 4 + b) * DI + d] * a2) * h;
  }
}

// phase 3: replay chunk from true h_init, emit y = (sum_n h*C + D*u)*silu(z)
// z gathered via INPUT map (gating is in sequence order); result scattered
// via OUTPUT (inverse) map.
__global__ __launch_bounds__(256) void scan_p3(
    const float* __restrict__ xc, const float* __restrict__ xdbl,
    const float* __restrict__ xz, const float* __restrict__ A2,
    const float* __restrict__ dtw, const float* __restrict__ dtbias,
    const float* __restrict__ hinit, const float* __restrict__ Dp,
    float* __restrict__ yacc, int mode, int accum) {
  __shared__ float Xl[CHL][40];
  const int c = blockIdx.x, b = blockIdx.y, d = threadIdx.x;
  const int p0 = c * CHL;
  for (int idx = threadIdx.x; idx < CHL * 40; idx += 256) {
    int pr = idx / 40, r = idx % 40;
    Xl[pr][r] = xdbl[((size_t)b * LSEQ + p0 + pr) * 40 + r];
  }
  float a2[NST], h[NST], dw[8];
  size_t hbase = (((size_t)c * 4 + b) * DI + d) * NST;
#pragma unroll
  for (int n = 0; n < NST; ++n) { a2[n] = A2[d * NST + n]; h[n] = hinit[hbase + n]; }
#pragma unroll
  for (int r = 0; r < 8; ++r) dw[r] = dtw[d * 8 + r];
  const float dbias = dtbias[d];
  const float Dv = Dp[d];
  __syncthreads();
  for (int pr = 0; pr < CHL; ++pr) {
    const size_t row = (size_t)b * LSEQ + p0 + pr;
    const float u = xc[row * DI + d];
    float raw = dbias;
#pragma unroll
    for (int r = 0; r < 8; ++r) raw = fmaf(dw[r], Xl[pr][r], raw);
    const float dtv = fsoftplus(raw);
    const float dtu = dtv * u;
    float y = Dv * u;
#pragma unroll
    for (int n = 0; n < NST; ++n) {
      float a = FEXP2(dtv * a2[n]);
      h[n] = fmaf(h[n], a, dtu * Xl[pr][8 + n]);
      y = fmaf(h[n], Xl[pr][24 + n], y);
    }
    const int lz = lmap(p0 + pr, mode);       // z gather (sequence order)
    const int lo = lmap_out(p0 + pr, mode);   // output scatter (inverse map)
    const float z = xz[((size_t)b * LSEQ + lz) * ED + DI + d];
    const float val = y * fsilu(z);
    float* o = yacc + ((size_t)b * LSEQ + lo) * DI + d;
    if (accum) *o += val; else *o = val;
  }
}

// out = x_mamba + nm_w*(x_mamba-mu)/sqrt(var+1e-6)+nm_b, x_mamba = x + yout^T
__global__ __launch_bounds__(256) void final_kernel(
    const float* __restrict__ x, const float* __restrict__ yout,
    const float* __restrict__ nmw, const float* __restrict__ nmb,
    float* __restrict__ out) {
  __shared__ float xt[CDIM][65];
  __shared__ float ps[4][64], pq[4][64];
  __shared__ float mu_s[64], rs_s[64];
  const int b = blockIdx.y, l0 = blockIdx.x * 64, tid = threadIdx.x;
  for (int idx = tid; idx < CDIM * 64; idx += 256) {
    int c = idx >> 6, ll = idx & 63;
    xt[c][ll] = x[((size_t)(b * CDIM + c)) * LSEQ + l0 + ll];
  }
  __syncthreads();
  for (int idx = tid; idx < 64 * CDIM; idx += 256) {
    int c = idx & 127, ll = idx >> 7;
    xt[c][ll] += yout[((size_t)(b * LSEQ + l0 + ll)) * CDIM + c];
  }
  __syncthreads();
  {
    int ll = tid & 63, grp = tid >> 6;
    float s = 0.f, q = 0.f;
    for (int c = grp * 32; c < grp * 32 + 32; ++c) {
      float v = xt[c][ll]; s += v; q += v * v;
    }
    ps[grp][ll] = s; pq[grp][ll] = q;
  }
  __syncthreads();
  if (tid < 64) {
    float S = ps[0][tid] + ps[1][tid] + ps[2][tid] + ps[3][tid];
    float Q = pq[0][tid] + pq[1][tid] + pq[2][tid] + pq[3][tid];
    float mu = S * (1.f / 128.f);
    float var = Q * (1.f / 128.f) - mu * mu;
    mu_s[tid] = mu;
    rs_s[tid] = rsqrtf(var + 1e-6f);
  }
  __syncthreads();
  for (int idx = tid; idx < CDIM * 64; idx += 256) {
    int c = idx >> 6, ll = idx & 63;
    float v = xt[c][ll];
    float nv = v + nmw[c] * (v - mu_s[ll]) * rs_s[ll] + nmb[c];
    out[((size_t)(b * CDIM + c)) * LSEQ + l0 + ll] = nv;
  }
}

extern "C" void kernel_launch(void* const* d_in, const int* in_sizes, int n_in,
                              void* d_out, int out_size, void* d_ws, size_t ws_size,
                              hipStream_t stream) {
  (void)in_sizes; (void)n_in; (void)out_size;
  const float* x         = (const float*)d_in[0];
  const float* ln_w      = (const float*)d_in[1];
  const float* ln_b      = (const float*)d_in[2];
  const float* in_proj_w = (const float*)d_in[3];
  const float* out_projw = (const float*)d_in[4];
  const float* conv_w[3] = {(const float*)d_in[5],  (const float*)d_in[12], (const float*)d_in[19]};
  const float* conv_b[3] = {(const float*)d_in[6],  (const float*)d_in[13], (const float*)d_in[20]};
  const float* xproj[3]  = {(const float*)d_in[7],  (const float*)d_in[14], (const float*)d_in[21]};
  const float* dtw[3]    = {(const float*)d_in[8],  (const float*)d_in[15], (const float*)d_in[22]};
  const float* dtb[3]    = {(const float*)d_in[9],  (const float*)d_in[16], (const float*)d_in[23]};
  const float* alog[3]   = {(const float*)d_in[10], (const float*)d_in[17], (const float*)d_in[24]};
  const float* Dvec[3]   = {(const float*)d_in[11], (const float*)d_in[18], (const float*)d_in[25]};
  const float* nm_w      = (const float*)d_in[26];
  const float* nm_b      = (const float*)d_in[27];

  float* ws    = (float*)d_ws;
  float* xn    = ws;              // 4718592 floats (reused as yout later)
  float* xz    = ws + 4718592;    // 18874368
  float* xc    = ws + 23592960;   // 9437184
  float* xdbl  = ws + 33030144;   // 1474560
  float* yacc  = ws + 34504704;   // 9437184
  float* A2    = ws + 43941888;   // 12288
  float* hout  = ws + 43954176;   // 2097152
  float* dts   = ws + 46051328;   // 131072
  float* hinit = ws + 46182400;   // 2097152  -> total 48279552 floats (193 MB)
  float* yout  = xn;
  if (ws_size < (size_t)48279552 * sizeof(float)) return;

  a2_kernel<<<48, 256, 0, stream>>>(alog[0], alog[1], alog[2], A2);
  ln_kernel<<<dim3(LSEQ / 64, 4), 256, 0, stream>>>(x, ln_w, ln_b, xn);
  // in_proj: (36864 x 128) @ (512 x 128)^T -> xz (B,L,512)
  gemm_kernel<<<dim3(576, 8), 256, 0, stream>>>(xn, in_proj_w, xz, 512, 128, 128, 512);

  for (int dir = 0; dir < 3; ++dir) {
    conv_kernel<<<dim3(LSEQ / 64, 4, 4), 256, 0, stream>>>(
        xz, conv_w[dir], conv_b[dir], xc, dir);
    // x_proj: (36864 x 256) @ (40 x 256)^T -> xdbl (B,L,40)
    gemm_kernel<<<dim3(576, 1), 256, 0, stream>>>(xc, xproj[dir], xdbl, 40, 256, 256, 40);
    scan_p1<<<dim3(NCH, 4), 256, 0, stream>>>(
        xc, xdbl, A2 + dir * 4096, dtw[dir], dtb[dir], hout, dts);
    scan_p2<<<64, 256, 0, stream>>>(hout, dts, A2 + dir * 4096, hinit);
    scan_p3<<<dim3(NCH, 4), 256, 0, stream>>>(
        xc, xdbl, xz, A2 + dir * 4096, dtw[dir], dtb[dir], hinit, Dvec[dir],
        yacc, dir, dir > 0 ? 1 : 0);
  }
  // out_proj: (36864 x 256) @ (128 x 256)^T -> yout (B,L,128)
  gemm_kernel<<<dim3(576, 2), 256, 0, stream>>>(yacc, out_projw, yout, 128, 256, 256, 128);
  final_kernel<<<dim3(LSEQ / 64, 4), 256, 0, stream>>>(x, yout, nm_w, nm_b, (float*)d_out);
}